// Round 11
// baseline (1067.113 us; speedup 1.0000x reference)
//
#include <hip/hip_runtime.h>
#include <hip/hip_bf16.h>
#include <hip/hip_fp8.h>

typedef __attribute__((ext_vector_type(4))) float f32x4;
typedef __attribute__((ext_vector_type(2))) long long ll2;

#define AS1 __attribute__((address_space(1)))
#define AS3 __attribute__((address_space(3)))

static constexpr int Mdim = 4096;
static constexpr int Kdim = 7168;
static constexpr int Ndim = 16384;
static constexpr int KB   = Kdim / 128;   // 56 scale blocks
static constexpr float FP8_MAX = 448.0f;

// compiler-fence + raw barrier (no implicit vmcnt(0) drain)
#define BARRIER() do { asm volatile("" ::: "memory"); \
                       __builtin_amdgcn_s_barrier();  \
                       asm volatile("" ::: "memory"); } while (0)

#define MFMA_FP8 __builtin_amdgcn_mfma_f32_16x16x32_fp8_fp8

// ---------------------------------------------------------------------------
// Kernel 1: activation quant  x[M,K] f32 -> xq[M,K] fp8  +  xs_t[KB][M] f32
// ---------------------------------------------------------------------------
__global__ __launch_bounds__(256) void quant_x_kernel(
    const float* __restrict__ x, unsigned char* __restrict__ xq,
    float* __restrict__ xst)
{
    constexpr int NBLK = Mdim * KB;
    const int lane = threadIdx.x & 63;
    const int wid  = (blockIdx.x * 256 + threadIdx.x) >> 6;
    const int nw   = (gridDim.x * 256) >> 6;

    for (int b = wid; b < NBLK; b += nw) {
        size_t base = (size_t)b * 128 + lane * 2;
        float2 v = *reinterpret_cast<const float2*>(x + base);
        float amax = fmaxf(fabsf(v.x), fabsf(v.y));
#pragma unroll
        for (int off = 32; off > 0; off >>= 1)
            amax = fmaxf(amax, __shfl_xor(amax, off));
        float s = amax * (1.0f / FP8_MAX);
        unsigned char q0 = 0, q1 = 0;
        if (s > 0.0f) {
            q0 = __hip_fp8_e4m3(v.x / s).__x;
            q1 = __hip_fp8_e4m3(v.y / s).__x;
        }
        *reinterpret_cast<unsigned short*>(xq + base) =
            (unsigned short)(q0 | ((unsigned short)q1 << 8));
        if (lane == 0) {
            int row = b / KB, kb = b - row * KB;
            xst[(size_t)kb * Mdim + row] = s;
        }
    }
}

// ---------------------------------------------------------------------------
// Kernel 2: weight quant  w[N,K] f32 -> w8[N,K] fp8 (plain RNE cast)
// ---------------------------------------------------------------------------
__global__ __launch_bounds__(256) void quant_w_kernel(
    const float* __restrict__ w, unsigned char* __restrict__ w8)
{
    constexpr size_t NCHUNK = (size_t)Ndim * Kdim / 8;

    size_t idx    = (size_t)blockIdx.x * 256 + threadIdx.x;
    size_t stride = (size_t)gridDim.x * 256;

    for (size_t c = idx; c < NCHUNK; c += stride) {
        const float* src = w + c * 8;
        float4 v0 = *reinterpret_cast<const float4*>(src);
        float4 v1 = *reinterpret_cast<const float4*>(src + 4);
        unsigned int lo = (unsigned int)__hip_fp8_e4m3(v0.x).__x
                        | ((unsigned int)__hip_fp8_e4m3(v0.y).__x << 8)
                        | ((unsigned int)__hip_fp8_e4m3(v0.z).__x << 16)
                        | ((unsigned int)__hip_fp8_e4m3(v0.w).__x << 24);
        unsigned int hi = (unsigned int)__hip_fp8_e4m3(v1.x).__x
                        | ((unsigned int)__hip_fp8_e4m3(v1.y).__x << 8)
                        | ((unsigned int)__hip_fp8_e4m3(v1.z).__x << 16)
                        | ((unsigned int)__hip_fp8_e4m3(v1.w).__x << 24);
        uint2 p; p.x = lo; p.y = hi;
        *reinterpret_cast<uint2*>(w8 + c * 8) = p;
    }
}

// ---------------------------------------------------------------------------
// Kernel 3: 128x256 NT GEMM, fp8-resident, 8 waves (2M x 4N), per-wave
// 64x64 output -> acc[4][4] = 64 f32/lane.  Register budget ~175/256: the
// VALU scale-merge can no longer spill (round-10 diagnosis).
//
// LDS map (78272 B):
//   [0,49152):      2 buf x { A@0, B0@8192, B1@16384 } of [128 rows][64 B fp8]
//   [49152,77824):  xs slice [56 kb][128 rows] f32 (rows bm..bm+128)
//   [77824,78272):  ws slice [2 nb][56 kb] f32
//
// b128 k-permutation reads (verified 0-conflict): lane reads 16 B at phys
// slot lk ^ ((lr>>1)&3); MFMA call 0 = lo 8 B, call 1 = hi 8 B; same
// permutation on A and B => exact dot product.  Staging source uses the
// same involution; LDS dest linear (wave-uniform base, HW adds lane*16).
//
// Stage calls (T, r): r 0:A 1:B0 2:B1, region (T&1)*24576 + r*8192, one
// 16B load/thread/call (region 8 KB = 512 thr x 16 B).
// Per tile t (buf = t&1):
//   W1: stage(t+1, A)@buf^1; read a(8), b0(4), b1(4); sv from LDS;
//       Q0 = 4m x {n0,n1}; lgkmcnt(0); BARRIER
//   W2: stage(t+2, B0/B1)@buf; Q1 = 4m x {n2,n3} (register-only);
//       vmcnt(2) [t<NT-2] else vmcnt(0); BARRIER
// Residency: outstanding after W2 = {A(t+1), B0(t+2), B1(t+2)} -> vmcnt(2)
// waits A(t+1); B(t+1) issued one tile earlier -> done. Overwrite safety:
// W1 writes A@buf^1 (reads are @buf); W2 writes B@buf with all B-reads
// drained by W1's lgkmcnt(0) before the W1->W2 barrier.
// ---------------------------------------------------------------------------
constexpr int BM = 128, BN = 256, BK = 64;
constexpr int NT  = Kdim / BK;            // 112 K-tiles
constexpr int NBN = Ndim / BN;            // 64
constexpr int NWG = (Mdim / BM) * NBN;    // 2048 (%8 == 0)
constexpr int K1  = Kdim;                 // fp8 row stride in bytes
constexpr int BUFSZ  = 24576;
constexpr int XS_OFF = 49152;
constexpr int WS_OFF = XS_OFF + 56 * 512;        // 77824
constexpr int LDS_TOT = WS_OFF + 448;            // 78272

__global__ __launch_bounds__(512, 2) void gemm128_fp8_kernel(
    const unsigned char* __restrict__ Ag,   // xq  [M][K] fp8
    const unsigned char* __restrict__ Bg,   // w8  [N][K] fp8
    const float* __restrict__ xsT,          // [KB][M] f32
    const float* __restrict__ Wsc,          // [N/128][KB] f32
    float* __restrict__ C)
{
    extern __shared__ char smem[];   // LDS_TOT bytes

    const int tid  = threadIdx.x;
    const int w    = tid >> 6;
    const int lane = tid & 63;
    const int wr   = w >> 2;          // 0..1 (M)
    const int wc   = w & 3;           // 0..3 (N)
    const int lr   = lane & 15;
    const int lk   = lane >> 4;

    // XCD-bijective block swizzle
    int bid = (int)blockIdx.x;
    int swz = (bid & 7) * (NWG >> 3) + (bid >> 3);
    const int bm = (swz / NBN) * BM;
    const int bn = (swz % NBN) * BN;

    // swizzled b128 read column (bytes within a 64-B row); lane-constant
    const int colF = (lk ^ ((lr >> 1) & 3)) << 4;
    const int aRow = wr * 64;         // wave's row base in A region
    const int bRow = (wc & 1) * 64;   // wave's row base in its B region

    // LDS scale bases
    const char* xsL0 = smem + XS_OFF + (wr * 64 + lk * 4) * 4;
    const char* wsL  = smem + WS_OFF + (wc >> 1) * (KB * 4);

    // staging: 1 chunk (16B) per thread per call (involution matches read)
    const int rowS = tid >> 2;                            // 0..127
    const int colS = (((tid & 3) ^ ((rowS >> 1) & 3))) * 16;
    const size_t offG = (size_t)rowS * K1 + colS;
    const int ldsW = w * 1024;        // wave-uniform; HW adds lane*16

    const char* Ab = (const char*)Ag + (size_t)bm * K1;
    const char* Bb = (const char*)Bg + (size_t)bn * K1;

    auto stage = [&](int T, int r) {   // r: 0=A, 1=B0, 2=B1
        if (T >= NT) return;
        const int regByte = (T & 1) * BUFSZ + r * 8192;
        const char* g = (r ? Bb + (size_t)(r - 1) * (128 * (size_t)K1) : Ab)
                        + (size_t)T * 64 + offG;
        __builtin_amdgcn_global_load_lds((const AS1 void*)g,
                                         (AS3 void*)(smem + regByte + ldsW),
                                         16, 0, 0);
    };

    // ---- prologue: scales, then tile0 {A,B0,B1} + tile1 {B0,B1} ----
    // xs: wave-chunk c = i*8+w covers kb = 2c + (lane>>5), rows (lane&31)*4
#pragma unroll
    for (int i = 0; i < 4; ++i) {
        const int c = i * 8 + w;
        if (c < 28) {
            const int kb  = 2 * c + (lane >> 5);
            const int row = (lane & 31) * 4;
            const float* g = xsT + (size_t)kb * Mdim + bm + row;
            __builtin_amdgcn_global_load_lds((const AS1 void*)g,
                (AS3 void*)(smem + XS_OFF + c * 1024), 16, 0, 0);
        }
    }
    if (w == 0 && lane < 28) {
        const float* g = Wsc + (size_t)(bn >> 7) * KB + lane * 4;
        __builtin_amdgcn_global_load_lds((const AS1 void*)g,
            (AS3 void*)(smem + WS_OFF), 16, 0, 0);
    }
    stage(0, 0); stage(0, 1); stage(0, 2);
    stage(1, 1); stage(1, 2);
    asm volatile("s_waitcnt vmcnt(2)" ::: "memory");  // scales + tile0 resident
    BARRIER();

    f32x4 acc[4][4] = {};

    for (int t = 0; t < NT; ++t) {
        const int buf = t & 1;
        const int kb  = t >> 1;
        const char* aB = smem + buf * BUFSZ;
        const char* bB = smem + buf * BUFSZ + 8192 + (wc >> 1) * 8192;
        ll2 a[4], b0[2], b1[2];
        f32x4 sv[4];

        const float wsv  = *(const float*)(wsL + kb * 4);
        const char* xsLk = xsL0 + kb * 512;

        // ================= W1 : Q0 (n0,n1) =================
        stage(t + 1, 0);                       // A(t+1) @ buf^1
#pragma unroll
        for (int m = 0; m < 4; ++m)
            a[m] = *(const ll2*)(aB + (aRow + m * 16 + lr) * 64 + colF);
#pragma unroll
        for (int n = 0; n < 2; ++n)
            b0[n] = *(const ll2*)(bB + (bRow + n * 16 + lr) * 64 + colF);
#pragma unroll
        for (int n = 0; n < 2; ++n)
            b1[n] = *(const ll2*)(bB + (bRow + (n + 2) * 16 + lr) * 64 + colF);
#pragma unroll
        for (int m = 0; m < 4; ++m)
            sv[m] = *reinterpret_cast<const f32x4*>(xsLk + m * 64) * wsv;
        __builtin_amdgcn_s_setprio(1);
#pragma unroll
        for (int m = 0; m < 4; ++m)
#pragma unroll
            for (int n = 0; n < 2; ++n) {
                f32x4 pacc = {0.f, 0.f, 0.f, 0.f};
                pacc = MFMA_FP8(a[m][0], b0[n][0], pacc, 0, 0, 0);
                pacc = MFMA_FP8(a[m][1], b0[n][1], pacc, 0, 0, 0);
                acc[m][n] += sv[m] * pacc;
            }
        __builtin_amdgcn_s_setprio(0);
        asm volatile("s_waitcnt lgkmcnt(0)" ::: "memory");  // b1 reads retired
        BARRIER();   // W1 -> W2

        // ================= W2 : Q1 (n2,n3) =================
        stage(t + 2, 1);                       // B0(t+2) @ buf
        stage(t + 2, 2);                       // B1(t+2) @ buf
        __builtin_amdgcn_s_setprio(1);
#pragma unroll
        for (int m = 0; m < 4; ++m)
#pragma unroll
            for (int n = 0; n < 2; ++n) {
                f32x4 pacc = {0.f, 0.f, 0.f, 0.f};
                pacc = MFMA_FP8(a[m][0], b1[n][0], pacc, 0, 0, 0);
                pacc = MFMA_FP8(a[m][1], b1[n][1], pacc, 0, 0, 0);
                acc[m][n + 2] += sv[m] * pacc;
            }
        __builtin_amdgcn_s_setprio(0);
        if (t < NT - 2) { asm volatile("s_waitcnt vmcnt(2)" ::: "memory"); }
        else            { asm volatile("s_waitcnt vmcnt(0)" ::: "memory"); }
        BARRIER();   // tile boundary: tile t+1 fully resident
    }

    // ---- epilogue: C/D layout col = lr, row = lk*4 + j ----
#pragma unroll
    for (int m = 0; m < 4; ++m) {
#pragma unroll
        for (int n = 0; n < 4; ++n) {
            const int row0 = bm + wr * 64 + m * 16 + lk * 4;
            const int col  = bn + wc * 64 + n * 16 + lr;
#pragma unroll
            for (int j = 0; j < 4; ++j)
                C[(size_t)(row0 + j) * Ndim + col] = acc[m][n][j];
        }
    }
}

// ---------------------------------------------------------------------------
extern "C" void kernel_launch(void* const* d_in, const int* in_sizes, int n_in,
                              void* d_out, int out_size, void* d_ws, size_t ws_size,
                              hipStream_t stream) {
    const float* x  = (const float*)d_in[0];
    const float* w  = (const float*)d_in[1];
    const float* ws = (const float*)d_in[2];

    unsigned char* xq  = (unsigned char*)d_ws;                       // 29.4 MB
    unsigned char* w8  = xq + (size_t)Mdim * Kdim;                   // 117.4 MB
    float*         xst = (float*)(w8 + (size_t)Ndim * Kdim);         // 0.92 MB

    quant_x_kernel<<<2048, 256, 0, stream>>>(x, xq, xst);
    quant_w_kernel<<<4096, 256, 0, stream>>>(w, w8);

    hipFuncSetAttribute((const void*)gemm128_fp8_kernel,
                        hipFuncAttributeMaxDynamicSharedMemorySize, LDS_TOT);
    gemm128_fp8_kernel<<<NWG, 512, LDS_TOT, stream>>>(xq, w8, xst, ws,
                                                      (float*)d_out);
}

// Round 12
// 1058.956 us; speedup vs baseline: 1.0077x; 1.0077x over previous
//
#include <hip/hip_runtime.h>
#include <hip/hip_bf16.h>
#include <hip/hip_fp8.h>

typedef __attribute__((ext_vector_type(4))) float f32x4;
typedef __attribute__((ext_vector_type(2))) long long ll2;

#define AS1 __attribute__((address_space(1)))
#define AS3 __attribute__((address_space(3)))

static constexpr int Mdim = 4096;
static constexpr int Kdim = 7168;
static constexpr int Ndim = 16384;
static constexpr int KB   = Kdim / 128;   // 56 scale blocks
static constexpr float FP8_MAX = 448.0f;

// compiler-fence + raw barrier (no implicit vmcnt(0) drain)
#define BARRIER() do { asm volatile("" ::: "memory"); \
                       __builtin_amdgcn_s_barrier();  \
                       asm volatile("" ::: "memory"); } while (0)

#define MFMA_FP8 __builtin_amdgcn_mfma_f32_16x16x32_fp8_fp8

// ---------------------------------------------------------------------------
// Kernel 1: activation quant  x[M,K] f32 -> xq[M,K] fp8  +  xs_t[KB][M] f32
// ---------------------------------------------------------------------------
__global__ __launch_bounds__(256) void quant_x_kernel(
    const float* __restrict__ x, unsigned char* __restrict__ xq,
    float* __restrict__ xst)
{
    constexpr int NBLK = Mdim * KB;
    const int lane = threadIdx.x & 63;
    const int wid  = (blockIdx.x * 256 + threadIdx.x) >> 6;
    const int nw   = (gridDim.x * 256) >> 6;

    for (int b = wid; b < NBLK; b += nw) {
        size_t base = (size_t)b * 128 + lane * 2;
        float2 v = *reinterpret_cast<const float2*>(x + base);
        float amax = fmaxf(fabsf(v.x), fabsf(v.y));
#pragma unroll
        for (int off = 32; off > 0; off >>= 1)
            amax = fmaxf(amax, __shfl_xor(amax, off));
        float s = amax * (1.0f / FP8_MAX);
        unsigned char q0 = 0, q1 = 0;
        if (s > 0.0f) {
            q0 = __hip_fp8_e4m3(v.x / s).__x;
            q1 = __hip_fp8_e4m3(v.y / s).__x;
        }
        *reinterpret_cast<unsigned short*>(xq + base) =
            (unsigned short)(q0 | ((unsigned short)q1 << 8));
        if (lane == 0) {
            int row = b / KB, kb = b - row * KB;
            xst[(size_t)kb * Mdim + row] = s;
        }
    }
}

// ---------------------------------------------------------------------------
// Kernel 2: weight quant  w[N,K] f32 -> w8[N,K] fp8 (plain RNE cast)
// ---------------------------------------------------------------------------
__global__ __launch_bounds__(256) void quant_w_kernel(
    const float* __restrict__ w, unsigned char* __restrict__ w8)
{
    constexpr size_t NCHUNK = (size_t)Ndim * Kdim / 8;

    size_t idx    = (size_t)blockIdx.x * 256 + threadIdx.x;
    size_t stride = (size_t)gridDim.x * 256;

    for (size_t c = idx; c < NCHUNK; c += stride) {
        const float* src = w + c * 8;
        float4 v0 = *reinterpret_cast<const float4*>(src);
        float4 v1 = *reinterpret_cast<const float4*>(src + 4);
        unsigned int lo = (unsigned int)__hip_fp8_e4m3(v0.x).__x
                        | ((unsigned int)__hip_fp8_e4m3(v0.y).__x << 8)
                        | ((unsigned int)__hip_fp8_e4m3(v0.z).__x << 16)
                        | ((unsigned int)__hip_fp8_e4m3(v0.w).__x << 24);
        unsigned int hi = (unsigned int)__hip_fp8_e4m3(v1.x).__x
                        | ((unsigned int)__hip_fp8_e4m3(v1.y).__x << 8)
                        | ((unsigned int)__hip_fp8_e4m3(v1.z).__x << 16)
                        | ((unsigned int)__hip_fp8_e4m3(v1.w).__x << 24);
        uint2 p; p.x = lo; p.y = hi;
        *reinterpret_cast<uint2*>(w8 + c * 8) = p;
    }
}

// ---------------------------------------------------------------------------
// Kernel 3: 256x256 NT GEMM, fp8-resident, 16 waves (4M x 4N), per-wave
// 64x64 -> acc[4][4]=64 f32/lane (spill-free, round-11 verified per-wave
// body) + BM=256 (small-fetch geometry, rounds 8-10 verified ~1.05 GB).
// 4 waves/SIMD of TLP.
//
// LDS map (123328 B):
//   [0,65536):       2 buf x { A[256 rows][64 B] @0, B[256 rows][64 B] @16384 }
//   [65536,122880):  xs slice [56 kb][256 rows] f32 (rows bm..bm+256)
//   [122880,123328): ws slice [2 nb][56 kb] f32
//
// b128 k-permutation reads (verified 0-conflict): lane reads 16 B at phys
// slot lk ^ ((lr>>1)&3); MFMA call 0 = lo 8 B, call 1 = hi 8 B; same
// permutation on A and B => exact dot product.  Staging source uses the
// same involution (phys slot tid&3 <- logical slot ^ ((row>>1)&3)); LDS
// dest linear (wave-uniform base + lane*16).
//
// Stage call (T, isB): one 16 KB region per call (1024 thr x 16 B), dest
// regByte = (T&1)*32768 + isB*16384, src rows (bm|bn)+tid>>2, col swizzled.
// Per tile t (buf = t&1):
//   W1: stage(t+1, A)@buf^1; read a(4xb128), b0,b1(4xb128); sv from LDS;
//       Q0 = 4m x {n0,n1}; lgkmcnt(0); BARRIER
//   W2: stage(t+2, B)@buf; Q1 = 4m x {n2,n3} (register-only);
//       vmcnt(1) [t<NT-2] else vmcnt(0); BARRIER
// Residency: outstanding after W2 = {A(t+1), B(t+2)}; vmcnt(1) waits
// A(t+1); B(t+1) was issued one tile earlier. Overwrite safety: W1 writes
// A@buf^1 (reads @buf); W2 writes B@buf with all B-reads drained by W1's
// lgkmcnt(0) before the W1->W2 barrier. Prologue: per-wave outstanding
// counts differ (xs/ws guards) but vmcnt(1) leaves only the newest call
// (tile1 B) in flight for every wave -> scales + tile0 resident.
// ---------------------------------------------------------------------------
constexpr int BM = 256, BN = 256, BK = 64;
constexpr int NT  = Kdim / BK;            // 112 K-tiles
constexpr int NBN = Ndim / BN;            // 64
constexpr int NWG = (Mdim / BM) * NBN;    // 1024 (%8 == 0)
constexpr int K1  = Kdim;                 // fp8 row stride in bytes
constexpr int BUFSZ  = 32768;
constexpr int XS_OFF = 65536;
constexpr int WS_OFF = XS_OFF + 56 * 1024;       // 122880
constexpr int LDS_TOT = WS_OFF + 448;            // 123328

__global__ __launch_bounds__(1024, 4) void gemm256_fp8_kernel(
    const unsigned char* __restrict__ Ag,   // xq  [M][K] fp8
    const unsigned char* __restrict__ Bg,   // w8  [N][K] fp8
    const float* __restrict__ xsT,          // [KB][M] f32
    const float* __restrict__ Wsc,          // [N/128][KB] f32
    float* __restrict__ C)
{
    extern __shared__ char smem[];   // LDS_TOT bytes

    const int tid  = threadIdx.x;
    const int w    = tid >> 6;        // 0..15
    const int lane = tid & 63;
    const int wr   = w >> 2;          // 0..3 (M)
    const int wc   = w & 3;           // 0..3 (N)
    const int lr   = lane & 15;
    const int lk   = lane >> 4;

    // XCD-bijective block swizzle
    int bid = (int)blockIdx.x;
    int swz = (bid & 7) * (NWG >> 3) + (bid >> 3);
    const int bm = (swz / NBN) * BM;
    const int bn = (swz % NBN) * BN;

    // swizzled b128 read column (bytes within a 64-B row); lane-constant
    const int colF = (lk ^ ((lr >> 1) & 3)) << 4;
    const int aRow = wr * 64;         // wave's row base in A region (0..255)
    const int bRow = wc * 64;         // wave's row base in B region (0..255)

    // LDS scale bases
    const char* xsL0 = smem + XS_OFF + (wr * 64 + lk * 4) * 4;
    const char* wsL  = smem + WS_OFF + (wc >> 1) * (KB * 4);

    // staging: 1 chunk (16B) per thread per call (involution matches read)
    const int rowS = tid >> 2;                            // 0..255
    const int colS = (((tid & 3) ^ ((rowS >> 1) & 3))) * 16;
    const size_t offG = (size_t)rowS * K1 + colS;
    const int ldsW = w * 1024;        // wave-uniform; HW adds lane*16

    const char* Ab = (const char*)Ag + (size_t)bm * K1;
    const char* Bb = (const char*)Bg + (size_t)bn * K1;

    auto stage = [&](int T, int isB) {
        if (T >= NT) return;
        const int regByte = (T & 1) * BUFSZ + isB * 16384;
        const char* g = (isB ? Bb : Ab) + (size_t)T * 64 + offG;
        __builtin_amdgcn_global_load_lds((const AS1 void*)g,
                                         (AS3 void*)(smem + regByte + ldsW),
                                         16, 0, 0);
    };

    // ---- prologue: scales (3584 xs chunks + 28 ws chunks), tile0, tile1-B --
#pragma unroll
    for (int i = 0; i < 4; ++i) {
        const int c = i * 1024 + tid;     // 16-B chunk of the xs slice
        if (c < 56 * 64) {                // i=3: only waves w<8 (wave-uniform)
            const int kb2 = c >> 6;
            const int row = (c & 63) * 4;
            const float* g = xsT + (size_t)kb2 * Mdim + bm + row;
            __builtin_amdgcn_global_load_lds((const AS1 void*)g,
                (AS3 void*)(smem + XS_OFF + i * 16384 + ldsW), 16, 0, 0);
        }
    }
    if (w == 0 && lane < 28) {
        const float* g = Wsc + (size_t)(bn >> 7) * KB + lane * 4;
        __builtin_amdgcn_global_load_lds((const AS1 void*)g,
            (AS3 void*)(smem + WS_OFF), 16, 0, 0);
    }
    stage(0, 0); stage(0, 1); stage(1, 1);
    asm volatile("s_waitcnt vmcnt(1)" ::: "memory");  // scales + tile0 resident
    BARRIER();

    f32x4 acc[4][4] = {};

    for (int t = 0; t < NT; ++t) {
        const int buf = t & 1;
        const int kb  = t >> 1;
        const char* aB = smem + buf * BUFSZ;
        const char* bB = smem + buf * BUFSZ + 16384;
        ll2 a[4], b0[2], b1[2];
        f32x4 sv[4];

        const float wsv  = *(const float*)(wsL + kb * 4);
        const char* xsLk = xsL0 + (kb << 10);

        // ================= W1 : Q0 (n0,n1) =================
        stage(t + 1, 0);                       // A(t+1) @ buf^1
#pragma unroll
        for (int m = 0; m < 4; ++m)
            a[m] = *(const ll2*)(aB + (aRow + m * 16 + lr) * 64 + colF);
#pragma unroll
        for (int n = 0; n < 2; ++n)
            b0[n] = *(const ll2*)(bB + (bRow + n * 16 + lr) * 64 + colF);
#pragma unroll
        for (int n = 0; n < 2; ++n)
            b1[n] = *(const ll2*)(bB + (bRow + (n + 2) * 16 + lr) * 64 + colF);
#pragma unroll
        for (int m = 0; m < 4; ++m)
            sv[m] = *reinterpret_cast<const f32x4*>(xsLk + m * 64) * wsv;
        __builtin_amdgcn_s_setprio(1);
#pragma unroll
        for (int m = 0; m < 4; ++m)
#pragma unroll
            for (int n = 0; n < 2; ++n) {
                f32x4 pacc = {0.f, 0.f, 0.f, 0.f};
                pacc = MFMA_FP8(a[m][0], b0[n][0], pacc, 0, 0, 0);
                pacc = MFMA_FP8(a[m][1], b0[n][1], pacc, 0, 0, 0);
                acc[m][n] += sv[m] * pacc;
            }
        __builtin_amdgcn_s_setprio(0);
        asm volatile("s_waitcnt lgkmcnt(0)" ::: "memory");  // B reads retired
        BARRIER();   // W1 -> W2

        // ================= W2 : Q1 (n2,n3) =================
        stage(t + 2, 1);                       // B(t+2) @ buf
        __builtin_amdgcn_s_setprio(1);
#pragma unroll
        for (int m = 0; m < 4; ++m)
#pragma unroll
            for (int n = 0; n < 2; ++n) {
                f32x4 pacc = {0.f, 0.f, 0.f, 0.f};
                pacc = MFMA_FP8(a[m][0], b1[n][0], pacc, 0, 0, 0);
                pacc = MFMA_FP8(a[m][1], b1[n][1], pacc, 0, 0, 0);
                acc[m][n + 2] += sv[m] * pacc;
            }
        __builtin_amdgcn_s_setprio(0);
        if (t < NT - 2) { asm volatile("s_waitcnt vmcnt(1)" ::: "memory"); }
        else            { asm volatile("s_waitcnt vmcnt(0)" ::: "memory"); }
        BARRIER();   // tile boundary: tile t+1 fully resident
    }

    // ---- epilogue: C/D layout col = lr, row = lk*4 + j ----
#pragma unroll
    for (int m = 0; m < 4; ++m) {
#pragma unroll
        for (int n = 0; n < 4; ++n) {
            const int row0 = bm + wr * 64 + m * 16 + lk * 4;
            const int col  = bn + wc * 64 + n * 16 + lr;
#pragma unroll
            for (int j = 0; j < 4; ++j)
                C[(size_t)(row0 + j) * Ndim + col] = acc[m][n][j];
        }
    }
}

// ---------------------------------------------------------------------------
extern "C" void kernel_launch(void* const* d_in, const int* in_sizes, int n_in,
                              void* d_out, int out_size, void* d_ws, size_t ws_size,
                              hipStream_t stream) {
    const float* x  = (const float*)d_in[0];
    const float* w  = (const float*)d_in[1];
    const float* ws = (const float*)d_in[2];

    unsigned char* xq  = (unsigned char*)d_ws;                       // 29.4 MB
    unsigned char* w8  = xq + (size_t)Mdim * Kdim;                   // 117.4 MB
    float*         xst = (float*)(w8 + (size_t)Ndim * Kdim);         // 0.92 MB

    quant_x_kernel<<<2048, 256, 0, stream>>>(x, xq, xst);
    quant_w_kernel<<<4096, 256, 0, stream>>>(w, w8);

    hipFuncSetAttribute((const void*)gemm256_fp8_kernel,
                        hipFuncAttributeMaxDynamicSharedMemorySize, LDS_TOT);
    gemm256_fp8_kernel<<<NWG, 1024, LDS_TOT, stream>>>(xq, w8, xst, ws,
                                                       (float*)d_out);
}